// Round 7
// baseline (313.985 us; speedup 1.0000x reference)
//
#include <hip/hip_runtime.h>

#define BN_EPS 1e-5f
typedef unsigned short u16;
typedef unsigned int u32;

// ws layout: stats = 72 floats at ws (sum1[28], ssq1[28], sum2[8], ssq2[8])
//   Psrc at ws+1024B : N*32 u16 (bf16, row stride 32 = 64B, 28 used)  3.2 MB
//   Pdst next        : N*32 u16                                        3.2 MB
//   y1   next        : E*28 u16 (bf16, PACKED 56B rows)               33.6 MB
//   y2   next        : E*8  u16 (bf16)                                 9.6 MB

__device__ __forceinline__ u16 f2bf(float f) {
  u32 u = __float_as_uint(f);
  return (u16)((u + 0x7fffu + ((u >> 16) & 1u)) >> 16);  // RNE
}
__device__ __forceinline__ float bf2f(u16 s) {
  return __uint_as_float(((u32)s) << 16);
}
__device__ __forceinline__ u32 pack2(float a, float b) {
  return (u32)f2bf(a) | ((u32)f2bf(b) << 16);
}

// K1 v3: wave-per-channel-set. lane = output channel (0..55; 56..63 dup/masked).
// Weights live in 128 VGPRs per lane (loaded once); h rows are wave-uniform
// -> s_load_dwordx4 feeding v_fma with SGPR operand. Node loop per wave.
// Also zeroes stats[0..72).
__global__ void __launch_bounds__(256) k1_proj(
    const float* __restrict__ h, const float* __restrict__ W1,
    u16* __restrict__ Psrc, u16* __restrict__ Pdst,
    float* __restrict__ stats, int N, int npw) {
  if (blockIdx.x == 0 && threadIdx.x < 72) stats[threadIdx.x] = 0.f;
  const int tid = threadIdx.x;
  const int lane = tid & 63;
  const int wid = (blockIdx.x * 256 + tid) >> 6;   // global wave id
  const int c = (lane < 56) ? lane : 55;           // channel 0..55
  // c<28: Psrc channel c = h . W1[c][0:128); c>=28: Pdst ch c-28 = h . W1[c-28][128:256)
  const float* wrow = (c < 28) ? (W1 + c * 268) : (W1 + (c - 28) * 268 + 128);
  float4 wreg[32];
#pragma unroll
  for (int q = 0; q < 32; q++) wreg[q] = ((const float4*)wrow)[q];  // per-lane, once

  int n0 = wid * npw;
  int n1 = n0 + npw;
  if (n1 > N) n1 = N;
  if (n0 > n1) n0 = n1;
  for (int n = n0; n < n1; n++) {
    const float4* h4 = (const float4*)(h + (size_t)n * 128);  // wave-uniform -> s_load
    float acc = 0.f;
#pragma unroll
    for (int q = 0; q < 32; q++) {
      const float4 a = h4[q];
      acc += a.x * wreg[q].x + a.y * wreg[q].y + a.z * wreg[q].z + a.w * wreg[q].w;
    }
    const u16 v = f2bf(acc);
    if (lane < 28)      Psrc[(size_t)n * 32 + lane] = v;        // 56B of one line
    else if (lane < 56) Pdst[(size_t)n * 32 + (lane - 28)] = v; // 56B of one line
  }
}

// K2 v5 (UNCHANGED from R6 — best measured, clean attribution this round).
__global__ void __launch_bounds__(256) k2_l1(
    const u16* __restrict__ Psrc, const u16* __restrict__ Pdst,
    const float* __restrict__ ef,
    const int* __restrict__ src, const int* __restrict__ dst,
    const float* __restrict__ W1, const float* __restrict__ b1,
    u16* __restrict__ y1, float* __restrict__ stats, int E, int epw) {
  const int tid = threadIdx.x;
  const int lane = tid & 63;
  const int c = lane & 31;
  const int g = tid >> 5;
  const int G = blockIdx.x * 8 + g;
  int e0 = G * epw;
  int e1 = e0 + epw;
  if (e1 > E) e1 = E;
  if (e0 > e1) e0 = e1;

  const bool act = (c < 28);
  float w[12];
#pragma unroll
  for (int j = 0; j < 12; j++) w[j] = 0.f;
  float bias = 0.f;
  if (act) {
    const float4* wp = (const float4*)(W1 + c * 268 + 256);
    float4 w0 = wp[0], w1 = wp[1], w2 = wp[2];
    w[0] = w0.x; w[1] = w0.y; w[2] = w0.z; w[3] = w0.w;
    w[4] = w1.x; w[5] = w1.y; w[6] = w1.z; w[7] = w1.w;
    w[8] = w2.x; w[9] = w2.y; w[10] = w2.z; w[11] = w2.w;
    bias = b1[c];
  }

  float sum = 0.f, ssq = 0.f;
  int e = e0;
  for (; e + 4 <= e1; e += 4) {
    const int4 sI = *(const int4*)(src + e);
    const int4 dI = *(const int4*)(dst + e);
    float pa[4], pb[4];
    pa[0] = bf2f(Psrc[(size_t)(u32)sI.x * 32 + c]);
    pa[1] = bf2f(Psrc[(size_t)(u32)sI.y * 32 + c]);
    pa[2] = bf2f(Psrc[(size_t)(u32)sI.z * 32 + c]);
    pa[3] = bf2f(Psrc[(size_t)(u32)sI.w * 32 + c]);
    pb[0] = bf2f(Pdst[(size_t)(u32)dI.x * 32 + c]);
    pb[1] = bf2f(Pdst[(size_t)(u32)dI.y * 32 + c]);
    pb[2] = bf2f(Pdst[(size_t)(u32)dI.z * 32 + c]);
    pb[3] = bf2f(Pdst[(size_t)(u32)dI.w * 32 + c]);
    float4 f0[4], f1[4], f2[4];
#pragma unroll
    for (int k = 0; k < 4; k++) {
      const float4* e4 = (const float4*)(ef + (size_t)(e + k) * 12);
      f0[k] = e4[0]; f1[k] = e4[1]; f2[k] = e4[2];
    }
#pragma unroll
    for (int k = 0; k < 4; k++) {
      float y = bias;
      y = fmaf(f0[k].x, w[0], y); y = fmaf(f0[k].y, w[1], y);
      y = fmaf(f0[k].z, w[2], y); y = fmaf(f0[k].w, w[3], y);
      y = fmaf(f1[k].x, w[4], y); y = fmaf(f1[k].y, w[5], y);
      y = fmaf(f1[k].z, w[6], y); y = fmaf(f1[k].w, w[7], y);
      y = fmaf(f2[k].x, w[8], y); y = fmaf(f2[k].y, w[9], y);
      y = fmaf(f2[k].z, w[10], y); y = fmaf(f2[k].w, w[11], y);
      y += pa[k] + pb[k];
      if (act) {
        sum += y;
        ssq += y * y;
        y1[(size_t)(e + k) * 28 + c] = f2bf(y);
      }
    }
  }
  for (; e < e1; e++) {
    const int sI = src[e], dI = dst[e];
    const float pa = bf2f(Psrc[(size_t)(u32)sI * 32 + c]);
    const float pb = bf2f(Pdst[(size_t)(u32)dI * 32 + c]);
    const float4* e4 = (const float4*)(ef + (size_t)e * 12);
    float4 f0 = e4[0], f1 = e4[1], f2 = e4[2];
    float y = bias;
    y = fmaf(f0.x, w[0], y); y = fmaf(f0.y, w[1], y);
    y = fmaf(f0.z, w[2], y); y = fmaf(f0.w, w[3], y);
    y = fmaf(f1.x, w[4], y); y = fmaf(f1.y, w[5], y);
    y = fmaf(f1.z, w[6], y); y = fmaf(f1.w, w[7], y);
    y = fmaf(f2.x, w[8], y); y = fmaf(f2.y, w[9], y);
    y = fmaf(f2.z, w[10], y); y = fmaf(f2.w, w[11], y);
    y += pa + pb;
    if (act) {
      sum += y;
      ssq += y * y;
      y1[(size_t)e * 28 + c] = f2bf(y);
    }
  }

  sum += __shfl_xor(sum, 32);
  ssq += __shfl_xor(ssq, 32);
  __shared__ float red[2][4][28];
  const int wave = tid >> 6;
  if (lane < 28) { red[0][wave][lane] = sum; red[1][wave][lane] = ssq; }
  __syncthreads();
  if (tid < 28) {
    atomicAdd(&stats[tid], red[0][0][tid] + red[0][1][tid] + red[0][2][tid] + red[0][3][tid]);
    atomicAdd(&stats[28 + tid], red[1][0][tid] + red[1][1][tid] + red[1][2][tid] + red[1][3][tid]);
  }
}

// K4 v3: LDS-staged tiles, NO nontemporal (y1 is L2-resident from k2), 4 tiles
// per block grid-stride. Stride-15 LDS rows: gcd(15,32)=1 -> <=2-way = free.
__global__ void __launch_bounds__(256) k4_l2(
    const u32* __restrict__ y1w, const float* __restrict__ stats,
    const float* __restrict__ g1, const float* __restrict__ be1,
    const float* __restrict__ W2, const float* __restrict__ b2,
    u16* __restrict__ y2, float* __restrict__ stats2, int E, float invE) {
  __shared__ u32 tile[256 * 15];
  float sc[28], sh[28];
#pragma unroll
  for (int cc = 0; cc < 28; cc++) {
    const float m = stats[cc] * invE;
    const float v = stats[28 + cc] * invE - m * m;
    const float s = g1[cc] * rsqrtf(v + BN_EPS);
    sc[cc] = s; sh[cc] = be1[cc] - m * s;
  }
  float as[8], aq[8];
#pragma unroll
  for (int o = 0; o < 8; o++) { as[o] = 0.f; aq[o] = 0.f; }
  const int tid = threadIdx.x;
  for (int T = blockIdx.x * 256; T < E; T += gridDim.x * 256) {
    int cnt = E - T; if (cnt > 256) cnt = 256;
    __syncthreads();
    const int total = cnt * 14;
    for (int i = tid; i < total; i += 256) {
      const int r = i / 14, j = i - r * 14;
      tile[r * 15 + j] = y1w[(size_t)T * 14 + i];   // coalesced, cached
    }
    __syncthreads();
    if (tid < cnt) {
      u32 uu[14];
#pragma unroll
      for (int i = 0; i < 14; i++) uu[i] = tile[tid * 15 + i];
      float acc[8];
#pragma unroll
      for (int o = 0; o < 8; o++) acc[o] = b2[o];
#pragma unroll
      for (int k = 0; k < 14; k++) {
        const float fe = __uint_as_float(uu[k] << 16);
        const float fo = __uint_as_float(uu[k] & 0xffff0000u);
        const float se = fmaxf(fmaf(fe, sc[2 * k], sh[2 * k]), 0.f);
        const float so = fmaxf(fmaf(fo, sc[2 * k + 1], sh[2 * k + 1]), 0.f);
#pragma unroll
        for (int o = 0; o < 8; o++) {
          acc[o] = fmaf(W2[o * 28 + 2 * k], se, acc[o]);      // uniform -> s_load
          acc[o] = fmaf(W2[o * 28 + 2 * k + 1], so, acc[o]);
        }
      }
      *(uint4*)(y2 + (size_t)(T + tid) * 8) =
          make_uint4(pack2(acc[0], acc[1]), pack2(acc[2], acc[3]),
                     pack2(acc[4], acc[5]), pack2(acc[6], acc[7]));
#pragma unroll
      for (int o = 0; o < 8; o++) { as[o] += acc[o]; aq[o] += acc[o] * acc[o]; }
    }
  }
#pragma unroll
  for (int o = 0; o < 8; o++) {
    for (int off = 32; off; off >>= 1) {
      as[o] += __shfl_down(as[o], off);
      aq[o] += __shfl_down(aq[o], off);
    }
  }
  __shared__ float redS[4][16];
  const int wave = tid >> 6, lane = tid & 63;
  if (lane == 0) {
#pragma unroll
    for (int o = 0; o < 8; o++) { redS[wave][o] = as[o]; redS[wave][8 + o] = aq[o]; }
  }
  __syncthreads();
  if (tid < 16) {
    atomicAdd(&stats2[tid], redS[0][tid] + redS[1][tid] + redS[2][tid] + redS[3][tid]);
  }
}

// K6: BN2 coefs per-thread, out = relu(BN2(y2)) @ W3.T + b3
__global__ void k6_l3(const u16* __restrict__ y2, const float* __restrict__ stats,
                      const float* __restrict__ g2, const float* __restrict__ be2,
                      const float* __restrict__ W3, const float* __restrict__ b3,
                      float* __restrict__ out, int E, float invE) {
  float sc[8], sh[8], w3[8];
#pragma unroll
  for (int o = 0; o < 8; o++) {
    const float m = stats[56 + o] * invE;
    const float v = stats[64 + o] * invE - m * m;
    const float s = g2[o] * rsqrtf(v + BN_EPS);
    sc[o] = s; sh[o] = be2[o] - m * s; w3[o] = W3[o];
  }
  const int e = blockIdx.x * blockDim.x + threadIdx.x;
  if (e >= E) return;
  const uint4 r = *(const uint4*)(y2 + (size_t)e * 8);
  u32 uu[4] = {r.x, r.y, r.z, r.w};
  float acc = b3[0];
#pragma unroll
  for (int k = 0; k < 4; k++) {
    const float fe = __uint_as_float(uu[k] << 16);
    const float fo = __uint_as_float(uu[k] & 0xffff0000u);
    acc = fmaf(w3[2 * k], fmaxf(fmaf(fe, sc[2 * k], sh[2 * k]), 0.f), acc);
    acc = fmaf(w3[2 * k + 1], fmaxf(fmaf(fo, sc[2 * k + 1], sh[2 * k + 1]), 0.f), acc);
  }
  out[e] = acc;
}

extern "C" void kernel_launch(void* const* d_in, const int* in_sizes, int n_in,
                              void* d_out, int out_size, void* d_ws, size_t ws_size,
                              hipStream_t stream) {
  const float* h   = (const float*)d_in[0];
  const float* ef  = (const float*)d_in[1];
  const int* src   = (const int*)d_in[2];
  const int* dst   = (const int*)d_in[3];
  const float* W1  = (const float*)d_in[4];
  const float* b1  = (const float*)d_in[5];
  const float* g1  = (const float*)d_in[6];
  const float* be1 = (const float*)d_in[7];
  const float* W2  = (const float*)d_in[8];
  const float* b2  = (const float*)d_in[9];
  const float* g2  = (const float*)d_in[10];
  const float* be2 = (const float*)d_in[11];
  const float* W3  = (const float*)d_in[12];
  const float* b3  = (const float*)d_in[13];
  float* out = (float*)d_out;

  const int N = in_sizes[0] / 128;
  const int E = in_sizes[2];
  const float invE = 1.0f / (float)E;

  char* ws = (char*)d_ws;
  float* stats = (float*)ws;                       // 72 floats
  u16* Psrc = (u16*)(ws + 1024);
  u16* Pdst = Psrc + (size_t)N * 32;
  u16* y1   = Pdst + (size_t)N * 32;               // E*28 packed
  u16* y2   = y1 + (size_t)E * 28;

  // k1: 512 blocks = 2048 waves; nodes per wave
  const int K1B = 512;
  const int npw = (N + K1B * 4 - 1) / (K1B * 4);
  k1_proj<<<K1B, 256, 0, stream>>>(h, W1, Psrc, Pdst, stats, N, npw);

  const int K2B = 2048;                            // 16384 half-wave groups
  int epw = (E + K2B * 8 - 1) / (K2B * 8);
  epw = (epw + 7) & ~7;                            // multiple of 8 -> aligned int4
  k2_l1<<<K2B, 256, 0, stream>>>(Psrc, Pdst, ef, src, dst, W1, b1, y1, stats, E, epw);

  const int K4B = (E + 1023) / 1024;               // 4 tiles per block
  k4_l2<<<K4B, 256, 0, stream>>>((const u32*)y1, stats, g1, be1, W2, b2, y2,
                                 stats + 56, E, invE);
  k6_l3<<<(E + 255) / 256, 256, 0, stream>>>(y2, stats, g2, be2, W3, b3, out, E, invE);
}